// Round 5
// baseline (587.421 us; speedup 1.0000x reference)
//
#include <hip/hip_runtime.h>
#include <hip/hip_bf16.h>

#define Nn 16384
#define Ff 39
#define Vv 100000
#define Ee 16
#define Dd 624      // F*E
#define KP1 640     // deep width padded (zero pad cols 624..639)
#define KP2 448     // x1 width padded  (zero pad cols 400..447)
#define Hh 400
#define EPSf 1e-5f
#define GRIDB 512

typedef short short8 __attribute__((ext_vector_type(8)));
typedef float floatx4 __attribute__((ext_vector_type(4)));

__device__ __forceinline__ unsigned short f2bu(float x) {
  __hip_bfloat16 h = __float2bfloat16(x);
  return *reinterpret_cast<unsigned short*>(&h);
}
__device__ __forceinline__ float bf2f(unsigned short v) {
  union { unsigned int u; float f; } x; x.u = ((unsigned int)v) << 16; return x.f;
}
__device__ __forceinline__ void gload16(void* lds, const void* g) {
  __builtin_amdgcn_global_load_lds(
      (const __attribute__((address_space(1))) unsigned int*)g,
      (__attribute__((address_space(3))) unsigned int*)lds, 16, 0, 0);
}

// ---- grid barrier: one single-use counter word per sync point, zeroed per-iteration
// by a captured hipMemsetAsync. Grid (512) <= worst-case co-resident capacity
// (launch_bounds(256,2): VGPR<=256 -> 2 blocks/CU x 256 CU = 512), so no deadlock.
__device__ __forceinline__ void gridbar(unsigned* bar, int id) {
  __syncthreads();
  if (threadIdx.x == 0) {
    __threadfence();                                   // release prior writes
    unsigned prev = atomicAdd(&bar[id], 1u);
    if (prev + 1u < (unsigned)GRIDB) {
      while (atomicAdd(&bar[id], 0u) < (unsigned)GRIDB)
        __builtin_amdgcn_s_sleep(2);
    }
    __threadfence();                                   // acquire
  }
  __syncthreads();
}

// ---------------- GEMM body (R3-proven): C = A(16384 x K) @ Wt^T + bias ----------------
// Single-buffered: stage(global_load_lds w16) -> barrier -> MFMA -> barrier.
// XOR-swizzle (kc ^= row&7) on BOTH global source chunk and ds_read slot (rule 21).
// tile in [0,640): XCD-bijective map. C==nullptr: stats-only (f32) epilogue.
__device__ __forceinline__ void gemm_body(
    const __hip_bfloat16* __restrict__ A, const __hip_bfloat16* __restrict__ Wt,
    const float* __restrict__ bias, __hip_bfloat16* __restrict__ C,
    float* __restrict__ s, float* __restrict__ ss, const int K, const int ldc,
    char* smem, const int tile) {
  short* As_s = (short*)smem;                    // 128*64*2 = 16384 B
  short* Bs_s = (short*)(smem + 16384);          // 80*64*2  = 10240 B
  float* redS = (float*)(smem + 16384 + 10240);  // 320 f
  float* redQ = redS + 320;                      // 320 f
  const int tid = threadIdx.x;
  const int v  = (tile & 7) * 80 + (tile >> 3);  // 640%8==0 -> bijective XCD chunks
  const int n0 = (v % 5) * 80;
  const int m0 = (v / 5) * 128;
  const int w = tid >> 6, lane = tid & 63;
  const int lm = lane & 15, qd = lane >> 4;

  floatx4 acc[2][5];
  #pragma unroll
  for (int i = 0; i < 2; ++i)
    #pragma unroll
    for (int j = 0; j < 5; ++j)
      acc[i][j] = (floatx4){0.f, 0.f, 0.f, 0.f};

  const int nk = K >> 6;
  for (int ks = 0; ks < nk; ++ks) {
    const int k0 = ks << 6;
    #pragma unroll
    for (int j = 0; j < 4; ++j) {
      const int c = tid + j * 256;
      const int m = c >> 3, kc = c & 7;
      gload16(&As_s[c * 8], &A[(size_t)(m0 + m) * K + k0 + ((kc ^ (m & 7)) << 3)]);
    }
    #pragma unroll
    for (int j = 0; j < 3; ++j) {
      const int c = tid + j * 256;
      if (c < 640) {
        const int nn = c >> 3, kc = c & 7;
        gload16(&Bs_s[c * 8], &Wt[(size_t)(n0 + nn) * K + k0 + ((kc ^ (nn & 7)) << 3)]);
      }
    }
    __syncthreads();
    #pragma unroll
    for (int h = 0; h < 2; ++h) {
      const int sl = h * 4 + qd;
      const int r0 = w * 32 + lm, r1 = r0 + 16;
      const short8 a0 = *(const short8*)&As_s[r0 * 64 + ((sl ^ (r0 & 7)) << 3)];
      const short8 a1 = *(const short8*)&As_s[r1 * 64 + ((sl ^ (r1 & 7)) << 3)];
      #pragma unroll
      for (int nt = 0; nt < 5; ++nt) {
        const int rn = nt * 16 + lm;
        const short8 bfr = *(const short8*)&Bs_s[rn * 64 + ((sl ^ (rn & 7)) << 3)];
        acc[0][nt] = __builtin_amdgcn_mfma_f32_16x16x32_bf16(a0, bfr, acc[0][nt], 0, 0, 0);
        acc[1][nt] = __builtin_amdgcn_mfma_f32_16x16x32_bf16(a1, bfr, acc[1][nt], 0, 0, 0);
      }
    }
    __syncthreads();
  }

  // epilogue: C/D layout col=lane&15, row=qd*4+reg
  const int rb = m0 + w * 32 + qd * 4;
  #pragma unroll
  for (int nt = 0; nt < 5; ++nt) {
    const int col = n0 + nt * 16 + lm;
    const float bc = bias[col];
    float cs = 0.f, cq = 0.f;
    #pragma unroll
    for (int mt = 0; mt < 2; ++mt) {
      #pragma unroll
      for (int r = 0; r < 4; ++r) {
        const float vv = acc[mt][nt][r] + bc;
        float vf = vv;
        if (C) {
          const __hip_bfloat16 hv = __float2bfloat16(vv);
          C[(size_t)(rb + mt * 16 + r) * ldc + col] = hv;
          vf = __bfloat162float(hv);
        }
        cs += vf; cq += vf * vf;
      }
    }
    cs += __shfl_xor(cs, 16); cq += __shfl_xor(cq, 16);
    cs += __shfl_xor(cs, 32); cq += __shfl_xor(cq, 32);
    if (lane < 16) { redS[w * 80 + nt * 16 + lm] = cs; redQ[w * 80 + nt * 16 + lm] = cq; }
  }
  __syncthreads();
  if (tid < 80) {
    const int nt = tid >> 4, l = tid & 15;
    const int col = n0 + nt * 16 + l;
    const int o = nt * 16 + l;
    atomicAdd(&s[col],  redS[o] + redS[80 + o] + redS[160 + o] + redS[240 + o]);
    atomicAdd(&ss[col], redQ[o] + redQ[80 + o] + redQ[160 + o] + redQ[240 + o]);
  }
}

// ---------------- prep2 body (R3-proven): W2t[n][k]=a1[k]*W2[k][n] (pad->448); b2p partials ----------------
__device__ __forceinline__ void prep2_body(
    const float* __restrict__ W2, const float* __restrict__ s1, const float* __restrict__ ss1,
    const float* __restrict__ g1, const float* __restrict__ be1, const float* __restrict__ b2,
    __hip_bfloat16* __restrict__ W2t, float* __restrict__ b2p, char* smem, const int tb) {
  float* sa = (float*)smem;
  float* sc = sa + 64;
  float (*Tt)[65] = (float(*)[65])(smem + 512);
  float* pcs = (float*)(smem + 512 + 16640);
  const int tk = tb / 7, tn = tb % 7;
  const int k0 = tk * 64, n0 = tn * 64;
  const int t = threadIdx.x;
  if (t < 64) {
    const int k = k0 + t;
    float a = 0.f, cv = 0.f;
    if (k < Hh) {
      const float mu = s1[k] * (1.f / Nn);
      const float var = ss1[k] * (1.f / Nn) - mu * mu;
      a = g1[k] * rsqrtf(var + EPSf);
      cv = be1[k] - a * mu;
    }
    sa[t] = a; sc[t] = cv;
  }
  __syncthreads();
  const int c = t & 63, r0 = (t >> 6) * 16;
  const int n = n0 + c;
  float pc = 0.f;
  #pragma unroll
  for (int r = r0; r < r0 + 16; ++r) {
    const int k = k0 + r;
    const float wv = (k < Hh && n < Hh) ? W2[(size_t)k * Hh + n] : 0.f;
    Tt[c][r] = sa[r] * wv;
    pc += sc[r] * wv;
  }
  pcs[t] = pc;
  __syncthreads();
  if (t < 64 && n0 + t < Hh) {
    float tot = pcs[t] + pcs[t + 64] + pcs[t + 128] + pcs[t + 192];
    if (k0 == 0) tot += b2[n0 + t];
    atomicAdd(&b2p[n0 + t], tot);
  }
  const int nl = t >> 2, kq = (t & 3) * 16;
  const int nw = n0 + nl;
  if (nw < Hh) {
    #pragma unroll
    for (int q = 0; q < 4; ++q) {
      const int kk = kq + q * 4;
      *(ushort4*)&W2t[(size_t)nw * KP2 + k0 + kk] = make_ushort4(
          f2bu(Tt[nl][kk]), f2bu(Tt[nl][kk + 1]),
          f2bu(Tt[nl][kk + 2]), f2bu(Tt[nl][kk + 3]));
    }
  }
}

// ---------------- prep3 body (R3-proven): u[k] = sum_h alpha[h]*W2t[h][k]; u[448] = const ----------------
__device__ __forceinline__ void prep3_body(
    const __hip_bfloat16* __restrict__ W2t, const float* __restrict__ s2,
    const float* __restrict__ ss2, const float* __restrict__ g2,
    const float* __restrict__ be2, const float* __restrict__ b2p,
    float* __restrict__ u, char* smem, const int blk) {
  float* sal  = (float*)smem;     // 400
  float* part = sal + Hh;         // 256
  float* red  = part + 256;       // 256
  const int t = threadIdx.x;
  float cpart = 0.f;
  for (int h = t; h < Hh; h += 256) {
    const float mu = s2[h] * (1.f / Nn);
    const float var = ss2[h] * (1.f / Nn) - mu * mu;
    const float al = g2[h] * rsqrtf(var + EPSf);
    sal[h] = al;
    cpart += be2[h] - al * mu + al * b2p[h];
  }
  __syncthreads();
  const int k = blk * 64 + (t & 63);
  const int hs = t >> 6;
  float acc = 0.f;
  for (int h = hs * 100; h < hs * 100 + 100; ++h)
    acc += sal[h] * bf2f(*(const unsigned short*)&W2t[(size_t)h * KP2 + k]);
  part[hs * 64 + (t & 63)] = acc;
  __syncthreads();
  if (t < 64) u[blk * 64 + t] = part[t] + part[64 + t] + part[128 + t] + part[192 + t];
  if (blk == 0) {
    red[t] = cpart;
    __syncthreads();
    for (int d = 128; d > 0; d >>= 1) { if (t < d) red[t] += red[t + d]; __syncthreads(); }
    if (t == 0) u[KP2] = red[0];
  }
}

// ---------------- fused persistent kernel: 6 phases, 5 atomic grid barriers ----------------
__global__ __launch_bounds__(256, 2) void fused(
    const int* __restrict__ xi, const float* __restrict__ xv,
    const float* __restrict__ emb1, const float* __restrict__ emb2,
    const float* __restrict__ W1, const float* __restrict__ b1,
    const float* __restrict__ g1, const float* __restrict__ be1,
    const float* __restrict__ W2, const float* __restrict__ b2,
    const float* __restrict__ g2, const float* __restrict__ be2,
    const float* __restrict__ bias, float* __restrict__ out,
    __hip_bfloat16* __restrict__ deep, __hip_bfloat16* __restrict__ x1b,
    __hip_bfloat16* __restrict__ W1t, __hip_bfloat16* __restrict__ W2t,
    float* __restrict__ p, float* __restrict__ stats, float* __restrict__ u,
    unsigned* __restrict__ bar) {
  __shared__ __align__(16) char smem[29184];
  const int blk = blockIdx.x, tid = threadIdx.x;
  const int w = tid >> 6, lane = tid & 63;
  float* s1  = stats;
  float* ss1 = stats + 400;
  float* s2  = stats + 800;
  float* ss2 = stats + 1200;
  float* b2p = stats + 1600;   // stats+u+bar zeroed by captured hipMemsetAsync

  // ===== Phase 0a: W1t coalesced transpose (blocks 0..69) =====
  if (blk < 70) {
    float (*Tt)[65] = (float(*)[65])smem;
    const int tk = blk / 7, tn = blk % 7;
    const int k0 = tk * 64, n0 = tn * 64;
    const int c = tid & 63, r0 = (tid >> 6) * 16;
    const int n = n0 + c;
    #pragma unroll
    for (int r = r0; r < r0 + 16; ++r) {
      const int k = k0 + r;
      Tt[c][r] = (k < Dd && n < Hh) ? W1[(size_t)k * Hh + n] : 0.f;
    }
    __syncthreads();
    const int nl = tid >> 2, kq = (tid & 3) * 16;
    const int nw = n0 + nl;
    if (nw < Hh) {
      #pragma unroll
      for (int q = 0; q < 4; ++q) {
        const int kk = kq + q * 4;
        *(ushort4*)&W1t[(size_t)nw * KP1 + k0 + kk] = make_ushort4(
            f2bu(Tt[nl][kk]), f2bu(Tt[nl][kk + 1]),
            f2bu(Tt[nl][kk + 2]), f2bu(Tt[nl][kk + 3]));
      }
    }
  }
  // ===== Phase 0b: embed grid-stride (all blocks), LDS idx broadcast =====
  {
    int*   sidx = (int*)smem;           // 4*40 ints
    float* sxv  = (float*)(smem + 640); // 4*40 floats
    const float4* e2v = (const float4*)emb2;
    const float bias0 = bias[0];
    for (int g = blk; g < 4096; g += GRIDB) {
      __syncthreads();                  // protect prev iteration's sidx reads / Tt reuse
      const int n = g * 4 + w;
      if (lane < Ff) {
        sidx[w * 40 + lane] = xi[n * Ff + lane];
        sxv [w * 40 + lane] = xv[n * Ff + lane];
      }
      __syncthreads();
      float e1v = 0.f;
      if (lane < Ff)
        e1v = emb1[(long)lane * (Vv + 1) + sidx[w * 40 + lane]] * sxv[w * 40 + lane];

      float se0 = 0.f, se1 = 0.f, se2 = 0.f, se3 = 0.f;
      float qe0 = 0.f, qe1 = 0.f, qe2 = 0.f, qe3 = 0.f;
      #pragma unroll
      for (int t = 0; t < 3; ++t) {
        const int j4 = lane + t * 64;
        if (j4 < 156) {
          const int f = j4 >> 2;
          float4 v = e2v[((long)f * (Vv + 1) + sidx[w * 40 + f]) * 4 + (j4 & 3)];
          const float xf = sxv[w * 40 + f];
          v.x *= xf; v.y *= xf; v.z *= xf; v.w *= xf;
          *(ushort4*)&deep[(size_t)n * KP1 + j4 * 4] =
              make_ushort4(f2bu(v.x), f2bu(v.y), f2bu(v.z), f2bu(v.w));
          se0 += v.x; qe0 += v.x * v.x;
          se1 += v.y; qe1 += v.y * v.y;
          se2 += v.z; qe2 += v.z * v.z;
          se3 += v.w; qe3 += v.w * v.w;
        }
      }
      if (lane < 4)  *(ushort4*)&deep[(size_t)n * KP1 + Dd + lane * 4] = make_ushort4(0, 0, 0, 0);
      if (lane < 12) *(ushort4*)&x1b [(size_t)n * KP2 + Hh + lane * 4] = make_ushort4(0, 0, 0, 0);

      #pragma unroll
      for (int d = 4; d < 64; d <<= 1) {
        se0 += __shfl_xor(se0, d); qe0 += __shfl_xor(qe0, d);
        se1 += __shfl_xor(se1, d); qe1 += __shfl_xor(qe1, d);
        se2 += __shfl_xor(se2, d); qe2 += __shfl_xor(qe2, d);
        se3 += __shfl_xor(se3, d); qe3 += __shfl_xor(qe3, d);
      }
      float val = 0.f;
      if (lane < 4)
        val = 0.5f * ((se0 * se0 - qe0) + (se1 * se1 - qe1) +
                      (se2 * se2 - qe2) + (se3 * se3 - qe3));
      val += e1v;
      #pragma unroll
      for (int d = 1; d < 64; d <<= 1) val += __shfl_xor(val, d);
      if (lane == 0) p[n] = val + bias0;
    }
  }
  gridbar(bar, 0);

  // ===== Phase 1: gemm1 (deep @ W1t^T + b1 -> x1b, stats s1/ss1); 640 tiles / 512 blocks =====
  for (int t = blk; t < 640; t += GRIDB)
    gemm_body(deep, W1t, b1, x1b, s1, ss1, KP1, KP2, smem, t);
  gridbar(bar, 1);

  // ===== Phase 2: prep2 =====
  if (blk < 49) prep2_body(W2, s1, ss1, g1, be1, b2, W2t, b2p, smem, blk);
  gridbar(bar, 2);

  // ===== Phase 3: gemm2 (x1b @ W2t^T + b2p, stats-only s2/ss2) =====
  for (int t = blk; t < 640; t += GRIDB)
    gemm_body(x1b, W2t, b2p, nullptr, s2, ss2, KP2, 0, smem, t);
  gridbar(bar, 3);

  // ===== Phase 4: prep3 =====
  if (blk < 7) prep3_body(W2t, s2, ss2, g2, be2, b2p, u, smem, blk);
  gridbar(bar, 4);

  // ===== Phase 5: final: out[n] = p[n] + dot(x1b[n,:], u) + cc =====
  {
    float* su = (float*)smem;
    __syncthreads();
    for (int i = tid; i < KP2 + 1; i += 256) su[i] = u[i];
    __syncthreads();
    const float cc = su[KP2];
    for (int g = blk; g < 4096; g += GRIDB) {
      const int n = g * 4 + w;
      const unsigned short* row = (const unsigned short*)(x1b + (size_t)n * KP2);
      float acc = 0.f;
      #pragma unroll
      for (int h0 = lane * 4; h0 < KP2; h0 += 256) {
        const ushort4 uv = *(const ushort4*)&row[h0];
        acc += bf2f(uv.x) * su[h0]     + bf2f(uv.y) * su[h0 + 1]
             + bf2f(uv.z) * su[h0 + 2] + bf2f(uv.w) * su[h0 + 3];
      }
      #pragma unroll
      for (int d = 1; d < 64; d <<= 1) acc += __shfl_xor(acc, d);
      if (lane == 0) out[n] = p[n] + acc + cc;
    }
  }
}

extern "C" void kernel_launch(void* const* d_in, const int* in_sizes, int n_in,
                              void* d_out, int out_size, void* d_ws, size_t ws_size,
                              hipStream_t stream) {
  const int*   xi   = (const int*)d_in[0];
  const float* xv   = (const float*)d_in[1];
  const float* emb1 = (const float*)d_in[2];
  const float* emb2 = (const float*)d_in[3];
  const float* W1   = (const float*)d_in[4];
  const float* b1   = (const float*)d_in[5];
  const float* g1   = (const float*)d_in[6];
  const float* be1  = (const float*)d_in[7];
  const float* W2   = (const float*)d_in[8];
  const float* b2   = (const float*)d_in[9];
  const float* g2   = (const float*)d_in[10];
  const float* be2  = (const float*)d_in[11];
  const float* bias = (const float*)d_in[12];
  float* out = (float*)d_out;

  char* ws = (char*)d_ws;
  __hip_bfloat16* deep = (__hip_bfloat16*)ws;  ws += (size_t)Nn * KP1 * 2;
  __hip_bfloat16* x1b  = (__hip_bfloat16*)ws;  ws += (size_t)Nn * KP2 * 2;
  __hip_bfloat16* W1t  = (__hip_bfloat16*)ws;  ws += (size_t)Hh * KP1 * 2;
  __hip_bfloat16* W2t  = (__hip_bfloat16*)ws;  ws += (size_t)Hh * KP2 * 2;
  float* p     = (float*)ws;  ws += (size_t)Nn * 4;
  float* stats = (float*)ws;  ws += 2000 * 4;     // s1,ss1,s2,ss2,b2p
  float* u     = (float*)ws;  ws += 449 * 4;
  unsigned* bar = (unsigned*)ws; ws += 8 * 4;

  // zero stats(2000f) + u(449f) + bar(8u) in one captured memset (9828 B)
  hipMemsetAsync(stats, 0, (2000 + 449 + 8) * 4, stream);
  fused<<<GRIDB, 256, 0, stream>>>(xi, xv, emb1, emb2, W1, b1, g1, be1,
                                   W2, b2, g2, be2, bias, out,
                                   deep, x1b, W1t, W2t, p, stats, u, bar);
}

// Round 6
// 418.846 us; speedup vs baseline: 1.4025x; 1.4025x over previous
//
#include <hip/hip_runtime.h>
#include <hip/hip_bf16.h>

#define Nn 16384
#define Ff 39
#define Vv 100000
#define Ee 16
#define Dd 624      // F*E
#define KP1 640     // deep width padded (zero pad cols 624..639)
#define KP2 448     // x1 width padded  (zero pad cols 400..447)
#define Hh 400
#define EPSf 1e-5f
#define NWORK 640   // gemm worker blocks

typedef short short8 __attribute__((ext_vector_type(8)));
typedef float floatx4 __attribute__((ext_vector_type(4)));

__device__ __forceinline__ unsigned short f2bu(float x) {
  __hip_bfloat16 h = __float2bfloat16(x);
  return *reinterpret_cast<unsigned short*>(&h);
}
__device__ __forceinline__ float bf2f(unsigned short v) {
  union { unsigned int u; float f; } x; x.u = ((unsigned int)v) << 16; return x.f;
}
__device__ __forceinline__ void gload16(void* lds, const void* g) {
  __builtin_amdgcn_global_load_lds(
      (const __attribute__((address_space(1))) unsigned int*)g,
      (__attribute__((address_space(3))) unsigned int*)lds, 16, 0, 0);
}

// ---------------- Kernel 1 (R3-proven) ----------------
// blocks [0,70): W1t 64x64 coalesced LDS-transpose tiles; block 70: zero stats+counters;
// blocks [71,71+4096): embed rows (1 wave/row, 4 rows/block), float4 gathers
__global__ __launch_bounds__(256) void embed_kernel(
    const int* __restrict__ xi, const float* __restrict__ xv,
    const float* __restrict__ emb1, const float* __restrict__ emb2,
    const float* __restrict__ bias, const float* __restrict__ W1,
    __hip_bfloat16* __restrict__ deep, float* __restrict__ p,
    __hip_bfloat16* __restrict__ W1t, float* __restrict__ stats,
    __hip_bfloat16* __restrict__ x1b) {
  const int b = blockIdx.x;
  __shared__ float Tt[64][65];
  __shared__ int   sidx[4][40];
  __shared__ float sxv[4][40];
  if (b < 70) {
    const int tk = b / 7, tn = b % 7;
    const int k0 = tk * 64, n0 = tn * 64;
    const int c = threadIdx.x & 63, r0 = (threadIdx.x >> 6) * 16;
    const int n = n0 + c;
    #pragma unroll
    for (int r = r0; r < r0 + 16; ++r) {
      const int k = k0 + r;
      Tt[c][r] = (k < Dd && n < Hh) ? W1[(size_t)k * Hh + n] : 0.f;
    }
    __syncthreads();
    const int nl = threadIdx.x >> 2, kq = (threadIdx.x & 3) * 16;
    const int nw = n0 + nl;
    if (nw < Hh) {
      #pragma unroll
      for (int q = 0; q < 4; ++q) {
        const int kk = kq + q * 4;
        *(ushort4*)&W1t[(size_t)nw * KP1 + k0 + kk] = make_ushort4(
            f2bu(Tt[nl][kk]), f2bu(Tt[nl][kk + 1]),
            f2bu(Tt[nl][kk + 2]), f2bu(Tt[nl][kk + 3]));
      }
    }
    return;
  }
  if (b == 70) {
    for (int i = threadIdx.x; i < 2008; i += 256) stats[i] = 0.f;  // stats + done-counters
    return;
  }
  const int w = threadIdx.x >> 6;
  const int lane = threadIdx.x & 63;
  const int n = (b - 71) * 4 + w;
  if (lane < Ff) {
    sidx[w][lane] = xi[n * Ff + lane];
    sxv[w][lane]  = xv[n * Ff + lane];
  }
  __syncthreads();

  float e1v = 0.f;
  if (lane < Ff)
    e1v = emb1[(long)lane * (Vv + 1) + sidx[w][lane]] * sxv[w][lane];

  const float4* e2v = (const float4*)emb2;
  float se0 = 0.f, se1 = 0.f, se2 = 0.f, se3 = 0.f;
  float qe0 = 0.f, qe1 = 0.f, qe2 = 0.f, qe3 = 0.f;
  #pragma unroll
  for (int t = 0; t < 3; ++t) {
    const int j4 = lane + t * 64;
    if (j4 < 156) {
      const int f = j4 >> 2;
      float4 v = e2v[((long)f * (Vv + 1) + sidx[w][f]) * 4 + (j4 & 3)];
      const float xf = sxv[w][f];
      v.x *= xf; v.y *= xf; v.z *= xf; v.w *= xf;
      *(ushort4*)&deep[(size_t)n * KP1 + j4 * 4] =
          make_ushort4(f2bu(v.x), f2bu(v.y), f2bu(v.z), f2bu(v.w));
      se0 += v.x; qe0 += v.x * v.x;
      se1 += v.y; qe1 += v.y * v.y;
      se2 += v.z; qe2 += v.z * v.z;
      se3 += v.w; qe3 += v.w * v.w;
    }
  }
  if (lane < 4)  *(ushort4*)&deep[(size_t)n * KP1 + Dd + lane * 4] = make_ushort4(0, 0, 0, 0);
  if (lane < 12) *(ushort4*)&x1b [(size_t)n * KP2 + Hh + lane * 4] = make_ushort4(0, 0, 0, 0);

  #pragma unroll
  for (int d = 4; d < 64; d <<= 1) {
    se0 += __shfl_xor(se0, d); qe0 += __shfl_xor(qe0, d);
    se1 += __shfl_xor(se1, d); qe1 += __shfl_xor(qe1, d);
    se2 += __shfl_xor(se2, d); qe2 += __shfl_xor(qe2, d);
    se3 += __shfl_xor(se3, d); qe3 += __shfl_xor(qe3, d);
  }
  float val = 0.f;
  if (lane < 4)
    val = 0.5f * ((se0 * se0 - qe0) + (se1 * se1 - qe1) +
                  (se2 * se2 - qe2) + (se3 * se3 - qe3));
  val += e1v;
  #pragma unroll
  for (int d = 1; d < 64; d <<= 1) val += __shfl_xor(val, d);
  if (lane == 0) p[n] = val + bias[0];
}

// ---------------- prep2 body (R3-proven): W2t[n][k]=a1[k]*W2[k][n] (pad->448); b2p partials ----------------
__device__ __forceinline__ void prep2_body(
    const float* __restrict__ W2, const float* __restrict__ s1, const float* __restrict__ ss1,
    const float* __restrict__ g1, const float* __restrict__ be1, const float* __restrict__ b2,
    __hip_bfloat16* __restrict__ W2t, float* __restrict__ b2p, char* smem, const int tb) {
  float* sa = (float*)smem;                       // 64
  float* sc = sa + 64;                            // 64
  float (*Tt)[65] = (float(*)[65])(smem + 512);   // 64*65*4 = 16640
  float* pcs = (float*)(smem + 512 + 16640);      // 256
  const int tk = tb / 7, tn = tb % 7;
  const int k0 = tk * 64, n0 = tn * 64;
  const int t = threadIdx.x;
  if (t < 64) {
    const int k = k0 + t;
    float a = 0.f, cv = 0.f;
    if (k < Hh) {
      const float mu = s1[k] * (1.f / Nn);
      const float var = ss1[k] * (1.f / Nn) - mu * mu;
      a = g1[k] * rsqrtf(var + EPSf);
      cv = be1[k] - a * mu;
    }
    sa[t] = a; sc[t] = cv;
  }
  __syncthreads();
  const int c = t & 63, r0 = (t >> 6) * 16;
  const int n = n0 + c;
  float pc = 0.f;
  #pragma unroll
  for (int r = r0; r < r0 + 16; ++r) {
    const int k = k0 + r;
    const float wv = (k < Hh && n < Hh) ? W2[(size_t)k * Hh + n] : 0.f;
    Tt[c][r] = sa[r] * wv;
    pc += sc[r] * wv;
  }
  pcs[t] = pc;
  __syncthreads();
  if (t < 64 && n0 + t < Hh) {
    float tot = pcs[t] + pcs[t + 64] + pcs[t + 128] + pcs[t + 192];
    if (k0 == 0) tot += b2[n0 + t];
    atomicAdd(&b2p[n0 + t], tot);
  }
  const int nl = t >> 2, kq = (t & 3) * 16;
  const int nw = n0 + nl;
  if (nw < Hh) {
    #pragma unroll
    for (int q = 0; q < 4; ++q) {
      const int kk = kq + q * 4;
      *(ushort4*)&W2t[(size_t)nw * KP2 + k0 + kk] = make_ushort4(
          f2bu(Tt[nl][kk]), f2bu(Tt[nl][kk + 1]),
          f2bu(Tt[nl][kk + 2]), f2bu(Tt[nl][kk + 3]));
    }
  }
}

// ---------------- prep3 body (R3-proven): u[k]=sum_h alpha[h]*W2t[h][k]; u[448]=const ----------------
__device__ __forceinline__ void prep3_body(
    const __hip_bfloat16* __restrict__ W2t, const float* __restrict__ s2,
    const float* __restrict__ ss2, const float* __restrict__ g2,
    const float* __restrict__ be2, const float* __restrict__ b2p,
    float* __restrict__ u, char* smem, const int blk) {
  float* sal  = (float*)smem;     // 400
  float* part = sal + Hh;         // 256
  float* red  = part + 256;       // 256
  const int t = threadIdx.x;
  float cpart = 0.f;
  for (int h = t; h < Hh; h += 256) {
    const float mu = s2[h] * (1.f / Nn);
    const float var = ss2[h] * (1.f / Nn) - mu * mu;
    const float al = g2[h] * rsqrtf(var + EPSf);
    sal[h] = al;
    cpart += be2[h] - al * mu + al * b2p[h];
  }
  __syncthreads();
  const int k = blk * 64 + (t & 63);
  const int hs = t >> 6;
  float acc = 0.f;
  for (int h = hs * 100; h < hs * 100 + 100; ++h)
    acc += sal[h] * bf2f(*(const unsigned short*)&W2t[(size_t)h * KP2 + k]);
  part[hs * 64 + (t & 63)] = acc;
  __syncthreads();
  if (t < 64) u[blk * 64 + t] = part[t] + part[64 + t] + part[128 + t] + part[192 + t];
  if (blk == 0) {
    red[t] = cpart;
    __syncthreads();
    for (int d = 128; d > 0; d >>= 1) { if (t < d) red[t] += red[t + d]; __syncthreads(); }
    if (t == 0) u[KP2] = red[0];
  }
}

// ---------------- bf16 MFMA GEMM + spin-tail ----------------
// Workers (blk<640): R3-proven single-buffered gload_lds loop, XOR-swizzle both-sides,
// XCD-bijective tile map, fused stats epilogue; then force stat-RMWs complete (use returned
// values), signal done-counter. Tail blocks (blk>=640): thread0 polls counter (few pollers,
// s_sleep -> no contention), then run prep2 (tailMode=1) or prep3 (tailMode=2).
// All 689/647 blocks co-resident (LDS 29.2KB -> 5 blocks/CU cap = 1280 slots): no deadlock.
__global__ __launch_bounds__(256) void gemm_bf16(
    const __hip_bfloat16* __restrict__ A, const __hip_bfloat16* __restrict__ Wt,
    const float* __restrict__ bias, __hip_bfloat16* __restrict__ C,
    float* __restrict__ s, float* __restrict__ ss, const int K, const int ldc,
    const int tailMode, unsigned* __restrict__ done,
    const float* __restrict__ W2, const float* __restrict__ gA,
    const float* __restrict__ beA, const float* __restrict__ b2,
    __hip_bfloat16* __restrict__ W2t, float* __restrict__ b2p,
    float* __restrict__ u) {
  __shared__ __align__(16) char smem[29184];
  const int tid = threadIdx.x;

  if (blockIdx.x >= NWORK) {                       // ---- tail block ----
    if (tid == 0) {
      while (atomicAdd(done, 0u) < (unsigned)NWORK) __builtin_amdgcn_s_sleep(16);
      __threadfence();                             // acquire
    }
    __syncthreads();
    const int tt = blockIdx.x - NWORK;
    if (tailMode == 1)
      prep2_body(W2, s, ss, gA, beA, b2, W2t, b2p, smem, tt);
    else
      prep3_body(W2t, s, ss, gA, beA, b2p, u, smem, tt);
    return;
  }

  short* As_s = (short*)smem;                      // 128*64*2 = 16384 B
  short* Bs_s = (short*)(smem + 16384);            // 80*64*2  = 10240 B
  float* redS = (float*)(smem + 16384 + 10240);    // 320 f
  float* redQ = redS + 320;                        // 320 f
  const int lin = blockIdx.x;
  const int v   = (lin & 7) * 80 + (lin >> 3);     // 640%8==0 -> bijective XCD chunks
  const int n0  = (v % 5) * 80;
  const int m0  = (v / 5) * 128;
  const int w = tid >> 6, lane = tid & 63;
  const int lm = lane & 15, qd = lane >> 4;

  floatx4 acc[2][5];
  #pragma unroll
  for (int i = 0; i < 2; ++i)
    #pragma unroll
    for (int j = 0; j < 5; ++j)
      acc[i][j] = (floatx4){0.f, 0.f, 0.f, 0.f};

  const int nk = K >> 6;
  for (int ks = 0; ks < nk; ++ks) {
    const int k0 = ks << 6;
    #pragma unroll
    for (int j = 0; j < 4; ++j) {
      const int c = tid + j * 256;
      const int m = c >> 3, kc = c & 7;
      gload16(&As_s[c * 8], &A[(size_t)(m0 + m) * K + k0 + ((kc ^ (m & 7)) << 3)]);
    }
    #pragma unroll
    for (int j = 0; j < 3; ++j) {
      const int c = tid + j * 256;
      if (c < 640) {
        const int nn = c >> 3, kc = c & 7;
        gload16(&Bs_s[c * 8], &Wt[(size_t)(n0 + nn) * K + k0 + ((kc ^ (nn & 7)) << 3)]);
      }
    }
    __syncthreads();
    #pragma unroll
    for (int h = 0; h < 2; ++h) {
      const int sl = h * 4 + qd;
      const int r0 = w * 32 + lm, r1 = r0 + 16;
      const short8 a0 = *(const short8*)&As_s[r0 * 64 + ((sl ^ (r0 & 7)) << 3)];
      const short8 a1 = *(const short8*)&As_s[r1 * 64 + ((sl ^ (r1 & 7)) << 3)];
      #pragma unroll
      for (int nt = 0; nt < 5; ++nt) {
        const int rn = nt * 16 + lm;
        const short8 bfr = *(const short8*)&Bs_s[rn * 64 + ((sl ^ (rn & 7)) << 3)];
        acc[0][nt] = __builtin_amdgcn_mfma_f32_16x16x32_bf16(a0, bfr, acc[0][nt], 0, 0, 0);
        acc[1][nt] = __builtin_amdgcn_mfma_f32_16x16x32_bf16(a1, bfr, acc[1][nt], 0, 0, 0);
      }
    }
    __syncthreads();
  }

  // epilogue: C/D layout col=lane&15, row=qd*4+reg
  const int rb = m0 + w * 32 + qd * 4;
  #pragma unroll
  for (int nt = 0; nt < 5; ++nt) {
    const int col = n0 + nt * 16 + lm;
    const float bc = bias[col];
    float cs = 0.f, cq = 0.f;
    #pragma unroll
    for (int mt = 0; mt < 2; ++mt) {
      #pragma unroll
      for (int r = 0; r < 4; ++r) {
        const float vv = acc[mt][nt][r] + bc;
        float vf = vv;
        if (C) {
          const __hip_bfloat16 hv = __float2bfloat16(vv);
          C[(size_t)(rb + mt * 16 + r) * ldc + col] = hv;
          vf = __bfloat162float(hv);
        }
        cs += vf; cq += vf * vf;
      }
    }
    cs += __shfl_xor(cs, 16); cq += __shfl_xor(cq, 16);
    cs += __shfl_xor(cs, 32); cq += __shfl_xor(cq, 32);
    if (lane < 16) { redS[w * 80 + nt * 16 + lm] = cs; redQ[w * 80 + nt * 16 + lm] = cq; }
  }
  __syncthreads();
  if (tid < 80) {
    const int nt = tid >> 4, l = tid & 15;
    const int col = n0 + nt * 16 + l;
    const int o = nt * 16 + l;
    // use returned values to force the RMWs complete before the done-signal
    float o1 = atomicAdd(&s[col],  redS[o] + redS[80 + o] + redS[160 + o] + redS[240 + o]);
    float o2 = atomicAdd(&ss[col], redQ[o] + redQ[80 + o] + redQ[160 + o] + redQ[240 + o]);
    __asm__ volatile("" :: "v"(o1), "v"(o2));
  }
  __syncthreads();
  if (tid == 0) {
    __threadfence();                               // release
    atomicAdd(done, 1u);
  }
}

// ---------------- final (R3-proven): out[n] = p[n] + dot(x1b[n,:], u) + cc ----------------
__global__ __launch_bounds__(256) void final_kernel(
    const __hip_bfloat16* __restrict__ x1, const float* __restrict__ u,
    const float* __restrict__ p, float* __restrict__ out) {
  __shared__ float su[KP2];
  __shared__ float scc;
  const int t = threadIdx.x;
  for (int i = t; i < KP2; i += 256) su[i] = u[i];
  if (t == 0) scc = u[KP2];
  __syncthreads();
  const int w = t >> 6, lane = t & 63;
  const int n = blockIdx.x * 4 + w;
  const unsigned short* row = (const unsigned short*)(x1 + (size_t)n * KP2);
  float acc = 0.f;
  #pragma unroll
  for (int h0 = lane * 4; h0 < KP2; h0 += 256) {
    const ushort4 uv = *(const ushort4*)&row[h0];
    acc += bf2f(uv.x) * su[h0]     + bf2f(uv.y) * su[h0 + 1]
         + bf2f(uv.z) * su[h0 + 2] + bf2f(uv.w) * su[h0 + 3];
  }
  #pragma unroll
  for (int d = 1; d < 64; d <<= 1) acc += __shfl_xor(acc, d);
  if (lane == 0) out[n] = p[n] + acc + scc;
}

extern "C" void kernel_launch(void* const* d_in, const int* in_sizes, int n_in,
                              void* d_out, int out_size, void* d_ws, size_t ws_size,
                              hipStream_t stream) {
  const int*   xi   = (const int*)d_in[0];
  const float* xv   = (const float*)d_in[1];
  const float* emb1 = (const float*)d_in[2];
  const float* emb2 = (const float*)d_in[3];
  const float* W1   = (const float*)d_in[4];
  const float* b1   = (const float*)d_in[5];
  const float* g1   = (const float*)d_in[6];
  const float* be1  = (const float*)d_in[7];
  const float* W2   = (const float*)d_in[8];
  const float* b2   = (const float*)d_in[9];
  const float* g2   = (const float*)d_in[10];
  const float* be2  = (const float*)d_in[11];
  const float* bias = (const float*)d_in[12];
  float* out = (float*)d_out;

  char* ws = (char*)d_ws;
  __hip_bfloat16* deep = (__hip_bfloat16*)ws;  ws += (size_t)Nn * KP1 * 2;
  __hip_bfloat16* x1b  = (__hip_bfloat16*)ws;  ws += (size_t)Nn * KP2 * 2;
  __hip_bfloat16* W1t  = (__hip_bfloat16*)ws;  ws += (size_t)Hh * KP1 * 2;
  __hip_bfloat16* W2t  = (__hip_bfloat16*)ws;  ws += (size_t)Hh * KP2 * 2;
  float* p     = (float*)ws;  ws += (size_t)Nn * 4;
  float* stats = (float*)ws;  ws += 2008 * 4;   // s1,ss1,s2,ss2,b2p + 8 counter words
  float* u     = (float*)ws;  ws += 449 * 4;

  float* s1  = stats;
  float* ss1 = stats + 400;
  float* s2  = stats + 800;
  float* ss2 = stats + 1200;
  float* b2p = stats + 1600;
  unsigned* done = (unsigned*)(stats + 2000);   // done[0]=gemm1, done[1]=gemm2 (zeroed by embed)

  embed_kernel<<<4167, 256, 0, stream>>>(xi, xv, emb1, emb2, bias, W1, deep, p, W1t, stats, x1b);
  // gemm1 (deep @ W1t^T + b1 -> x1b, stats s1/ss1) + prep2 tail (49 blocks)
  gemm_bf16<<<NWORK + 49, 256, 0, stream>>>(deep, W1t, b1, x1b, s1, ss1, KP1, KP2,
                                            1, done + 0, W2, g1, be1, b2, W2t, b2p, u);
  // gemm2 (x1b @ W2t^T + b2p, stats-only s2/ss2) + prep3 tail (7 blocks)
  gemm_bf16<<<NWORK + 7, 256, 0, stream>>>(x1b, W2t, b2p, nullptr, s2, ss2, KP2, 0,
                                           2, done + 1, W2, g2, be2, b2, W2t, b2p, u);
  final_kernel<<<Nn / 4, 256, 0, stream>>>(x1b, u, p, out);
}

// Round 7
// 380.575 us; speedup vs baseline: 1.5435x; 1.1006x over previous
//
#include <hip/hip_runtime.h>
#include <hip/hip_bf16.h>

#define Nn 16384
#define Ff 39
#define Vv 100000
#define Ee 16
#define Dd 624      // F*E
#define KP1 640     // deep width padded to multiple of 64 (zero pad cols 624..639)
#define KP2 448     // x1 width padded to multiple of 64  (zero pad cols 400..447)
#define Hh 400
#define EPSf 1e-5f

typedef short short8 __attribute__((ext_vector_type(8)));
typedef float floatx4 __attribute__((ext_vector_type(4)));

__device__ __forceinline__ unsigned short f2bu(float x) {
  __hip_bfloat16 h = __float2bfloat16(x);
  return *reinterpret_cast<unsigned short*>(&h);
}
__device__ __forceinline__ float bf2f(unsigned short v) {
  union { unsigned int u; float f; } x; x.u = ((unsigned int)v) << 16; return x.f;
}

// async global->LDS, 16B per lane. LDS dst must be wave-uniform base + lane*16.
__device__ __forceinline__ void gload16(void* lds, const void* g) {
  __builtin_amdgcn_global_load_lds(
      (const __attribute__((address_space(1))) unsigned int*)g,
      (__attribute__((address_space(3))) unsigned int*)lds, 16, 0, 0);
}

// ---------------- Kernel 1: embedding gather + FM  |  W1 transpose->bf16 (pad to 640) | zero stats ----------------
// blocks [0,4096): embed rows (1 wave/row, 4 rows/block), float4 gathers
// blocks [4096,4496): W1t[n][k] = bf16(W1[k][n]), k<624, zero pad k 624..639
// block 4496: zero the 4*400 stat accumulators
__global__ __launch_bounds__(256) void embed_kernel(
    const int* __restrict__ xi, const float* __restrict__ xv,
    const float* __restrict__ emb1, const float* __restrict__ emb2,
    const float* __restrict__ bias, const float* __restrict__ W1,
    __hip_bfloat16* __restrict__ deep, float* __restrict__ p,
    __hip_bfloat16* __restrict__ W1t, float* __restrict__ stats,
    __hip_bfloat16* __restrict__ x1b) {
  const int b = blockIdx.x;
  if (b >= 4096) {
    if (b == 4496) {
      for (int i = threadIdx.x; i < 1600; i += 256) stats[i] = 0.f;
    } else {
      const int n = b - 4096;
      for (int k = threadIdx.x; k < KP1; k += 256)
        W1t[(size_t)n * KP1 + k] =
            (k < Dd) ? __float2bfloat16(W1[(size_t)k * Hh + n]) : __float2bfloat16(0.f);
    }
    return;
  }
  __shared__ int   sidx[4][40];
  __shared__ float sxv[4][40];
  const int w = threadIdx.x >> 6;
  const int lane = threadIdx.x & 63;
  const int n = b * 4 + w;
  if (lane < Ff) {
    sidx[w][lane] = xi[n * Ff + lane];
    sxv[w][lane]  = xv[n * Ff + lane];
  }
  __syncthreads();

  // 156 float4 chunks per row; lane handles j4 = lane, lane+64, lane+128.
  // element e = (j4&3)*4 + c -> per-lane e-quad is constant = (lane&3)*4..+3
  const float4* e2v = (const float4*)emb2;
  float se0 = 0.f, se1 = 0.f, se2 = 0.f, se3 = 0.f;
  float qe0 = 0.f, qe1 = 0.f, qe2 = 0.f, qe3 = 0.f;
  #pragma unroll
  for (int t = 0; t < 3; ++t) {
    const int j4 = lane + t * 64;
    if (j4 < 156) {
      const int f = j4 >> 2;
      float4 v = e2v[((long)f * (Vv + 1) + sidx[w][f]) * 4 + (j4 & 3)];
      const float xf = sxv[w][f];
      v.x *= xf; v.y *= xf; v.z *= xf; v.w *= xf;
      *(ushort4*)&deep[(size_t)n * KP1 + j4 * 4] =
          make_ushort4(f2bu(v.x), f2bu(v.y), f2bu(v.z), f2bu(v.w));
      se0 += v.x; qe0 += v.x * v.x;
      se1 += v.y; qe1 += v.y * v.y;
      se2 += v.z; qe2 += v.z * v.z;
      se3 += v.w; qe3 += v.w * v.w;
    }
  }
  // zero pads: deep cols [624,640), x1b cols [400,448)
  if (lane < 4)  *(ushort4*)&deep[(size_t)n * KP1 + Dd + lane * 4] = make_ushort4(0, 0, 0, 0);
  if (lane < 12) *(ushort4*)&x1b [(size_t)n * KP2 + Hh + lane * 4] = make_ushort4(0, 0, 0, 0);

  // sum over f: combine lanes with equal (lane&3)
  #pragma unroll
  for (int d = 4; d < 64; d <<= 1) {
    se0 += __shfl_xor(se0, d); qe0 += __shfl_xor(qe0, d);
    se1 += __shfl_xor(se1, d); qe1 += __shfl_xor(qe1, d);
    se2 += __shfl_xor(se2, d); qe2 += __shfl_xor(qe2, d);
    se3 += __shfl_xor(se3, d); qe3 += __shfl_xor(qe3, d);
  }
  float val = 0.f;
  if (lane < 4)
    val = 0.5f * ((se0 * se0 - qe0) + (se1 * se1 - qe1) +
                  (se2 * se2 - qe2) + (se3 * se3 - qe3));
  if (lane < Ff)
    val += emb1[(long)lane * (Vv + 1) + sidx[w][lane]] * sxv[w][lane];
  #pragma unroll
  for (int d = 1; d < 64; d <<= 1) val += __shfl_xor(val, d);
  if (lane == 0) p[n] = val + bias[0];
}

// ---------------- bf16 MFMA GEMM: C(16384 x 400) = A(16384 x K) @ Wt^T + bias ----------------
// Wt PRE-TRANSPOSED [n][k], K padded to mult of 64 (zero pads). Block tile 128M x 80N, BK=64,
// 4 waves, wave tile 32M x 80N. Staging via global_load_lds width-16 into LINEAR LDS with
// XOR-swizzle (kc ^= row&7) applied to BOTH the global source chunk and the ds_read slot
// (rule 21: both-sides involution) -> 2-way (free) bank conflicts on fragment reads.
// XCD-aware bijective swizzle of the 640-block grid: each XCD gets contiguous m-range x all
// 5 n-tiles -> A panel reused 5x from in-XCD L2, Wt (<=0.5MB) resident per-XCD.
// Fused epilogue: bf16 store + LDS-combined (4 waves) per-column sum/sumsq atomics.
__global__ __launch_bounds__(256) void gemm_bf16(
    const __hip_bfloat16* __restrict__ A, const __hip_bfloat16* __restrict__ Wt,
    const float* __restrict__ bias, __hip_bfloat16* __restrict__ C,
    float* __restrict__ s, float* __restrict__ ss, const int K, const int ldc) {
  __shared__ __align__(16) short As_s[128 * 64];
  __shared__ __align__(16) short Bs_s[80 * 64];
  __shared__ float redS[4][5][16], redQ[4][5][16];
  const int tid = threadIdx.x;
  const int lin = blockIdx.x + blockIdx.y * 5;          // 0..639, 640%8==0 -> bijective
  const int v   = (lin & 7) * 80 + (lin >> 3);          // XCD c -> contiguous chunk c*80..
  const int n0  = (v % 5) * 80;
  const int m0  = (v / 5) * 128;
  const int w = tid >> 6, lane = tid & 63;
  const int lm = lane & 15, qd = lane >> 4;

  floatx4 acc[2][5];
  #pragma unroll
  for (int i = 0; i < 2; ++i)
    #pragma unroll
    for (int j = 0; j < 5; ++j)
      acc[i][j] = (floatx4){0.f, 0.f, 0.f, 0.f};

  const int nk = K >> 6;
  for (int ks = 0; ks < nk; ++ks) {
    const int k0 = ks << 6;
    // stage A: 1024 16B-chunks, chunk c=(m,kc): LDS slot c holds global chunk (m, kc^(m&7))
    #pragma unroll
    for (int j = 0; j < 4; ++j) {
      const int c = tid + j * 256;
      const int m = c >> 3, kc = c & 7;
      gload16(&As_s[c * 8], &A[(size_t)(m0 + m) * K + k0 + ((kc ^ (m & 7)) << 3)]);
    }
    // stage B: 640 16B-chunks (last pass: waves 0,1 only -> full-exec waves)
    #pragma unroll
    for (int j = 0; j < 3; ++j) {
      const int c = tid + j * 256;
      if (c < 640) {
        const int nn = c >> 3, kc = c & 7;
        gload16(&Bs_s[c * 8], &Wt[(size_t)(n0 + nn) * K + k0 + ((kc ^ (nn & 7)) << 3)]);
      }
    }
    __syncthreads();
    #pragma unroll
    for (int h = 0; h < 2; ++h) {
      const int sl = (h * 32 + qd * 8) >> 3;   // 16B slot index within row
      const int r0 = w * 32 + lm, r1 = r0 + 16;
      const short8 a0 = *(const short8*)&As_s[r0 * 64 + ((sl ^ (r0 & 7)) << 3)];
      const short8 a1 = *(const short8*)&As_s[r1 * 64 + ((sl ^ (r1 & 7)) << 3)];
      #pragma unroll
      for (int nt = 0; nt < 5; ++nt) {
        const int rn = nt * 16 + lm;
        const short8 bfr = *(const short8*)&Bs_s[rn * 64 + ((sl ^ (rn & 7)) << 3)];
        acc[0][nt] = __builtin_amdgcn_mfma_f32_16x16x32_bf16(a0, bfr, acc[0][nt], 0, 0, 0);
        acc[1][nt] = __builtin_amdgcn_mfma_f32_16x16x32_bf16(a1, bfr, acc[1][nt], 0, 0, 0);
      }
    }
    __syncthreads();
  }

  // epilogue: C/D layout col=lane&15, row=qd*4+reg
  const int rb = m0 + w * 32 + qd * 4;
  #pragma unroll
  for (int nt = 0; nt < 5; ++nt) {
    const int col = n0 + nt * 16 + lm;
    const float bc = bias[col];
    float cs = 0.f, cq = 0.f;
    #pragma unroll
    for (int mt = 0; mt < 2; ++mt) {
      #pragma unroll
      for (int r = 0; r < 4; ++r) {
        const float vv = acc[mt][nt][r] + bc;
        const __hip_bfloat16 hv = __float2bfloat16(vv);
        C[(size_t)(rb + mt * 16 + r) * ldc + col] = hv;
        const float vf = __bfloat162float(hv);
        cs += vf; cq += vf * vf;
      }
    }
    cs += __shfl_xor(cs, 16); cq += __shfl_xor(cq, 16);
    cs += __shfl_xor(cs, 32); cq += __shfl_xor(cq, 32);
    if (lane < 16) { redS[w][nt][lm] = cs; redQ[w][nt][lm] = cq; }
  }
  __syncthreads();
  if (tid < 80) {  // combine the 4 waves -> one atomic pair per column per block
    const int nt = tid >> 4, l = tid & 15;
    const int col = n0 + nt * 16 + l;
    atomicAdd(&s[col],  redS[0][nt][l] + redS[1][nt][l] + redS[2][nt][l] + redS[3][nt][l]);
    atomicAdd(&ss[col], redQ[0][nt][l] + redQ[1][nt][l] + redQ[2][nt][l] + redQ[3][nt][l]);
  }
}

// ---------------- prep2 (BN1 coefficients inline): W2t[n][k] = a1[k]*W2[k][n] (pad->448); b2p[n] = b2[n] + sum_k c1[k]*W2[k][n] ----------------
__global__ __launch_bounds__(256) void prep2_kernel(
    const float* __restrict__ W2,
    const float* __restrict__ s1, const float* __restrict__ ss1,
    const float* __restrict__ g1, const float* __restrict__ be1,
    const float* __restrict__ b2, __hip_bfloat16* __restrict__ W2t, float* __restrict__ b2p) {
  __shared__ float sa1[Hh], sc1[Hh];
  __shared__ float red[256];
  const int n = blockIdx.x, t = threadIdx.x;
  for (int k = t; k < Hh; k += 256) {
    const float mu = s1[k] * (1.f / Nn);
    const float var = ss1[k] * (1.f / Nn) - mu * mu;
    const float a = g1[k] * rsqrtf(var + EPSf);
    sa1[k] = a;
    sc1[k] = be1[k] - a * mu;
  }
  __syncthreads();
  float acc = 0.f;
  for (int k = t; k < KP2; k += 256) {
    if (k < Hh) {
      const float wv = W2[(size_t)k * Hh + n];
      W2t[(size_t)n * KP2 + k] = __float2bfloat16(sa1[k] * wv);
      acc += sc1[k] * wv;
    } else {
      W2t[(size_t)n * KP2 + k] = __float2bfloat16(0.f);
    }
  }
  red[t] = acc; __syncthreads();
  for (int d = 128; d > 0; d >>= 1) { if (t < d) red[t] += red[t + d]; __syncthreads(); }
  if (t == 0) b2p[n] = b2[n] + red[0];
}

// ---------------- final (BN2 alpha/c2 inline): out[n] = p[n] + dot(alpha, x2[n,:]) + c2 ----------------
__global__ __launch_bounds__(256) void final_kernel(
    const __hip_bfloat16* __restrict__ x2,
    const float* __restrict__ s2, const float* __restrict__ ss2,
    const float* __restrict__ g2, const float* __restrict__ be2,
    const float* __restrict__ p, float* __restrict__ out) {
  __shared__ float sal[Hh];
  __shared__ float red[256];
  const int t = threadIdx.x;
  float part = 0.f;
  for (int h = t; h < Hh; h += 256) {
    const float mu = s2[h] * (1.f / Nn);
    const float var = ss2[h] * (1.f / Nn) - mu * mu;
    const float al = g2[h] * rsqrtf(var + EPSf);
    sal[h] = al;
    part += be2[h] - al * mu;
  }
  red[t] = part; __syncthreads();
  for (int d = 128; d > 0; d >>= 1) { if (t < d) red[t] += red[t + d]; __syncthreads(); }
  __syncthreads();
  const float c2 = red[0];

  const int w = t >> 6, lane = t & 63;
  const int n = blockIdx.x * 4 + w;
  const unsigned short* row = (const unsigned short*)(x2 + (size_t)n * Hh);
  float acc = 0.f;
  for (int h0 = lane * 4; h0 < Hh; h0 += 256) {
    const ushort4 u = *(const ushort4*)&row[h0];
    acc += bf2f(u.x) * sal[h0] + bf2f(u.y) * sal[h0 + 1]
         + bf2f(u.z) * sal[h0 + 2] + bf2f(u.w) * sal[h0 + 3];
  }
  #pragma unroll
  for (int d = 1; d < 64; d <<= 1) acc += __shfl_xor(acc, d);
  if (lane == 0) out[n] = p[n] + acc + c2;
}

extern "C" void kernel_launch(void* const* d_in, const int* in_sizes, int n_in,
                              void* d_out, int out_size, void* d_ws, size_t ws_size,
                              hipStream_t stream) {
  const int*   xi   = (const int*)d_in[0];
  const float* xv   = (const float*)d_in[1];
  const float* emb1 = (const float*)d_in[2];
  const float* emb2 = (const float*)d_in[3];
  const float* W1   = (const float*)d_in[4];
  const float* b1   = (const float*)d_in[5];
  const float* g1   = (const float*)d_in[6];
  const float* be1  = (const float*)d_in[7];
  const float* W2   = (const float*)d_in[8];
  const float* b2   = (const float*)d_in[9];
  const float* g2   = (const float*)d_in[10];
  const float* be2  = (const float*)d_in[11];
  const float* bias = (const float*)d_in[12];
  float* out = (float*)d_out;

  char* ws = (char*)d_ws;
  __hip_bfloat16* deep = (__hip_bfloat16*)ws;  ws += (size_t)Nn * KP1 * 2;
  __hip_bfloat16* x1b  = (__hip_bfloat16*)ws;  ws += (size_t)Nn * KP2 * 2;
  __hip_bfloat16* x2b  = (__hip_bfloat16*)ws;  ws += (size_t)Nn * Hh * 2;
  __hip_bfloat16* W1t  = (__hip_bfloat16*)ws;  ws += (size_t)Hh * KP1 * 2;
  __hip_bfloat16* W2t  = (__hip_bfloat16*)ws;  ws += (size_t)Hh * KP2 * 2;
  float* p    = (float*)ws;  ws += (size_t)Nn * 4;
  float* s1   = (float*)ws;  ws += Hh * 4;   // s1,ss1,s2,ss2 contiguous (zeroed by embed launch)
  float* ss1  = (float*)ws;  ws += Hh * 4;
  float* s2   = (float*)ws;  ws += Hh * 4;
  float* ss2  = (float*)ws;  ws += Hh * 4;
  float* b2p  = (float*)ws;  ws += Hh * 4;

  embed_kernel<<<4497, 256, 0, stream>>>(xi, xv, emb1, emb2, bias, W1, deep, p, W1t, s1, x1b);
  gemm_bf16<<<dim3(5, Nn / 128), 256, 0, stream>>>(deep, W1t, b1, x1b, s1, ss1, KP1, KP2);
  prep2_kernel<<<Hh, 256, 0, stream>>>(W2, s1, ss1, g1, be1, b2, W2t, b2p);
  gemm_bf16<<<dim3(5, Nn / 128), 256, 0, stream>>>(x1b, W2t, b2p, x2b, s2, ss2, KP2, Hh);
  final_kernel<<<Nn / 4, 256, 0, stream>>>(x2b, s2, ss2, g2, be2, p, out);
}